// Round 7
// baseline (41.470 us; speedup 1.0000x reference)
//
#include <hip/hip_runtime.h>

#define B_SZ     2
#define E_EDGES  16384
#define N_NODES  4096
#define NTOT     (B_SZ * N_NODES)   // 8192 nodes
#define NV       (B_SZ * E_EDGES)   // 32768 edges / queries
#define DVTOT    128
#define LOG2_E   14
#define CAP      32                 // bucket capacity (Poisson(4): P(>=32) ~ 1e-19)

// padded LDS index: insert 4-float gap every 16 floats -> head h starts at h*20
__device__ __forceinline__ int padidx(int f) { return f + ((f >> 4) << 2); }

__device__ __forceinline__ float2 ntload2(const float* p) {
    unsigned long long u = __builtin_nontemporal_load((const unsigned long long*)p);
    union { unsigned long long u; float2 f; } cv; cv.u = u; return cv.f;
}
__device__ __forceinline__ void ntstore2(float* p, float2 v) {
    union { unsigned long long u; float2 f; } cv; cv.f = v;
    __builtin_nontemporal_store(cv.u, (unsigned long long*)p);
}
__device__ __forceinline__ int2 ntload_i2(const int* p) {
    unsigned long long u = __builtin_nontemporal_load((const unsigned long long*)p);
    union { unsigned long long u; int2 i; } cv; cv.u = u; return cv.i;
}

__global__ __launch_bounds__(256) void zero_counts(int* __restrict__ p) {
    int i = blockIdx.x * blockDim.x + threadIdx.x;   // 4096 threads of int4
    ((int4*)p)[i] = make_int4(0, 0, 0, 0);
}

// One pass over all 32768 edges/queries: bucket edges by col-node, queries by q-node.
__global__ __launch_bounds__(256) void fill_all(
    const int* __restrict__ qidx,
    const int* __restrict__ vidx,
    int*  __restrict__ ecnt,   // NTOT
    int*  __restrict__ qcnt,   // NTOT
    int2* __restrict__ ebuf,   // NTOT*CAP  {edge e, global key row}
    int*  __restrict__ qbuf)   // NTOT*CAP  query e | (suppress<<31)
{
    int e = blockIdx.x * blockDim.x + threadIdx.x;
    if (e >= NV) return;
    int ofs = (e >> LOG2_E) * N_NODES;

    int2 vi = ntload_i2(vidx + 2 * e);
    int row = vi.x + ofs;
    int col = vi.y + ofs;
    int p = atomicAdd(&ecnt[col], 1);
    if (p < CAP) ebuf[col * CAP + p] = make_int2(e, row);

    int2 qi = ntload_i2(qidx + 2 * e);
    int g  = qi.y + ofs;
    int pq = atomicAdd(&qcnt[g], 1);
    if (pq < CAP) qbuf[g * CAP + pq] = e | ((qi.x == qi.y) ? 0x80000000 : 0);
}

// One node per WAVE (4 nodes / 256-thread block), no block barriers.
// lane l: head h = l>>3, columns j = 2*(l&7), +1.  q-side chunk 0 prefetched
// before the k-loop so both global-latency chains overlap.
__global__ __launch_bounds__(256) void attn_node(
    const float* __restrict__ qv,
    const float* __restrict__ keys,
    const float* __restrict__ vals,
    const int*   __restrict__ ecnt,
    const int2*  __restrict__ ebuf,
    const int*   __restrict__ qcnt,
    const int*   __restrict__ qbuf,
    float*       __restrict__ out)
{
    __shared__ float sk[4][4][160];   // [wave][chunk][padded row]
    __shared__ float sq[4][4][160];

    int wid  = threadIdx.x >> 6;
    int lane = threadIdx.x & 63;
    int g    = blockIdx.x * 4 + wid;

    int nq = qcnt[g];  if (nq > CAP) nq = CAP;
    if (nq == 0) return;                 // wave-uniform
    int deg = ecnt[g]; if (deg > CAP) deg = CAP;

    int h20 = (lane >> 3) * 20;          // padded head base in LDS row
    int f2  = 2 * lane;                  // this lane's 2 floats of a 128-row
    int pf2 = padidx(f2);

    // ---- prefetch q chunk 0 (records + rows -> sq) before the k-chain ----
    const int* ql = qbuf + (size_t)g * CAP;
    int nq0 = (nq > 4) ? 4 : nq;
    int t0[4];
#pragma unroll
    for (int c = 0; c < 4; ++c)
        if (c < nq0) t0[c] = ql[c];                  // uniform -> s_load
#pragma unroll
    for (int c = 0; c < 4; ++c)
        if (c < nq0) {
            float2 qq = ntload2(qv + (size_t)(t0[c] & 0x7FFFFFFF) * DVTOT + f2);
            *(float2*)&sq[wid][c][pf2] = qq;
        }

    float kva[16], kvb[16], ks[16];
#pragma unroll
    for (int i = 0; i < 16; ++i) { kva[i] = 0.0f; kvb[i] = 0.0f; ks[i] = 0.0f; }

    const int2* eb = ebuf + (size_t)g * CAP;
    for (int base = 0; base < deg; base += 4) {
        int n = deg - base; if (n > 4) n = 4;        // wave-uniform
        int2 r[4]; float2 v[4];
#pragma unroll
        for (int c = 0; c < 4; ++c)
            if (c < n) r[c] = eb[base + c];
#pragma unroll
        for (int c = 0; c < 4; ++c)
            if (c < n) {
                float2 kk = *(const float2*)(keys + (size_t)r[c].y * DVTOT + f2);
                *(float2*)&sk[wid][c][pf2] = kk;     // coalesced stage
                v[c] = ntload2(vals + (size_t)r[c].x * DVTOT + f2);
            }
        __builtin_amdgcn_wave_barrier();             // order DS write -> DS read
#pragma unroll
        for (int c = 0; c < 4; ++c)
            if (c < n) {
                const float4* kp = (const float4*)&sk[wid][c][h20];
                float4 k0 = kp[0], k1 = kp[1], k2 = kp[2], k3 = kp[3];
                float kk[16] = {k0.x,k0.y,k0.z,k0.w, k1.x,k1.y,k1.z,k1.w,
                                k2.x,k2.y,k2.z,k2.w, k3.x,k3.y,k3.z,k3.w};
#pragma unroll
                for (int i = 0; i < 16; ++i) {
                    ks[i]  += kk[i];
                    kva[i] += kk[i] * v[c].x;
                    kvb[i] += kk[i] * v[c].y;
                }
            }
        __builtin_amdgcn_wave_barrier();             // order reads before next writes
    }

    // ---- q chunk 0 compute (rows already staged) ----
#pragma unroll
    for (int c = 0; c < 4; ++c)
        if (c < nq0) {
            const float4* qp = (const float4*)&sq[wid][c][h20];
            float4 q0 = qp[0], q1 = qp[1], q2 = qp[2], q3 = qp[3];
            float qq[16] = {q0.x,q0.y,q0.z,q0.w, q1.x,q1.y,q1.z,q1.w,
                            q2.x,q2.y,q2.z,q2.w, q3.x,q3.y,q3.z,q3.w};
            float sa = 0.0f, sb = 0.0f, w = 0.0f;
#pragma unroll
            for (int i = 0; i < 16; ++i) {
                sa += qq[i] * kva[i];
                sb += qq[i] * kvb[i];
                w  += qq[i] * ks[i];
            }
            float den = (w == 0.0f) ? 1e-5f : w;
            float inv = 1.0f / den;
            float2 o;
            o.x = (t0[c] < 0) ? 0.0f : sa * inv;
            o.y = (t0[c] < 0) ? 0.0f : sb * inv;
            ntstore2(out + (size_t)(t0[c] & 0x7FFFFFFF) * DVTOT + f2, o);
        }
    __builtin_amdgcn_wave_barrier();

    // ---- rare remainder: nq > 4 ----
    for (int base = 4; base < nq; base += 4) {
        int n = nq - base; if (n > 4) n = 4;         // wave-uniform
        int t[4];
#pragma unroll
        for (int c = 0; c < 4; ++c)
            if (c < n) t[c] = ql[base + c];
#pragma unroll
        for (int c = 0; c < 4; ++c)
            if (c < n) {
                float2 qq = ntload2(qv + (size_t)(t[c] & 0x7FFFFFFF) * DVTOT + f2);
                *(float2*)&sq[wid][c][pf2] = qq;
            }
        __builtin_amdgcn_wave_barrier();
#pragma unroll
        for (int c = 0; c < 4; ++c)
            if (c < n) {
                const float4* qp = (const float4*)&sq[wid][c][h20];
                float4 q0 = qp[0], q1 = qp[1], q2 = qp[2], q3 = qp[3];
                float qq[16] = {q0.x,q0.y,q0.z,q0.w, q1.x,q1.y,q1.z,q1.w,
                                q2.x,q2.y,q2.z,q2.w, q3.x,q3.y,q3.z,q3.w};
                float sa = 0.0f, sb = 0.0f, w = 0.0f;
#pragma unroll
                for (int i = 0; i < 16; ++i) {
                    sa += qq[i] * kva[i];
                    sb += qq[i] * kvb[i];
                    w  += qq[i] * ks[i];
                }
                float den = (w == 0.0f) ? 1e-5f : w;
                float inv = 1.0f / den;
                float2 o;
                o.x = (t[c] < 0) ? 0.0f : sa * inv;
                o.y = (t[c] < 0) ? 0.0f : sb * inv;
                ntstore2(out + (size_t)(t[c] & 0x7FFFFFFF) * DVTOT + f2, o);
            }
        __builtin_amdgcn_wave_barrier();
    }
}

extern "C" void kernel_launch(void* const* d_in, const int* in_sizes, int n_in,
                              void* d_out, int out_size, void* d_ws, size_t ws_size,
                              hipStream_t stream) {
    const float* qv   = (const float*)d_in[0];
    const float* keys = (const float*)d_in[1];
    const float* vals = (const float*)d_in[2];
    const int*   qidx = (const int*)d_in[3];
    const int*   vidx = (const int*)d_in[4];
    float* out = (float*)d_out;

    char* ws = (char*)d_ws;
    int*  ecnt = (int*)ws;                       // NTOT
    int*  qcnt = ecnt + NTOT;                    // NTOT
    int2* ebuf = (int2*)(ws + 65536);            // NTOT*CAP*8 = 2 MB
    int*  qbuf = (int*)(ws + 65536 + NTOT * CAP * 8); // NTOT*CAP*4 = 1 MB

    zero_counts<<<16, 256, 0, stream>>>(ecnt);   // zeros ecnt+qcnt (2*NTOT ints)
    fill_all<<<(NV + 255) / 256, 256, 0, stream>>>(qidx, vidx, ecnt, qcnt, ebuf, qbuf);
    attn_node<<<NTOT / 4, 256, 0, stream>>>(qv, keys, vals, ecnt, ebuf, qcnt, qbuf, out);
}

// Round 8
// 31.461 us; speedup vs baseline: 1.3181x; 1.3181x over previous
//
#include <hip/hip_runtime.h>

#define B_SZ     2
#define E_EDGES  16384
#define N_NODES  4096
#define NTOT     (B_SZ * N_NODES)   // 8192 nodes
#define NV       (B_SZ * E_EDGES)   // 32768 edges / queries
#define DVTOT    128
#define LOG2_E   14
#define CAP      32                 // bucket capacity (Poisson(4): P(>=32) ~ 1e-19)

// ws layout (contiguous zero region):
//   ecnt[NTOT] | qcnt[NTOT] | ebuf[NTOT*CAP] int2 | qbuf[NTOT*CAP] int
// total = 64KB + 2MB + 1MB = 3,211,264 B = 200704 int4
#define ZERO_INT4 200704

// padded LDS index: insert 4-float gap every 16 floats -> head h starts at h*20
__device__ __forceinline__ int padidx(int f) { return f + ((f >> 4) << 2); }

__global__ __launch_bounds__(256) void zero_ws(int4* __restrict__ p) {
    int i = blockIdx.x * blockDim.x + threadIdx.x;
    p[i] = make_int4(0, 0, 0, 0);
}

// One pass over all 32768 edges/queries: bucket edges by col-node, queries by
// q-node. Records are sentinel-coded (e+1) so the consumer never reads counts.
__global__ __launch_bounds__(256) void fill_all(
    const int* __restrict__ qidx,
    const int* __restrict__ vidx,
    int*  __restrict__ ecnt,   // NTOT (cursors only)
    int*  __restrict__ qcnt,   // NTOT (cursors only)
    int2* __restrict__ ebuf,   // NTOT*CAP  {e+1, global key row}
    int*  __restrict__ qbuf)   // NTOT*CAP  (e+1) | (suppress<<31)
{
    int e = blockIdx.x * blockDim.x + threadIdx.x;
    if (e >= NV) return;
    int ofs = (e >> LOG2_E) * N_NODES;

    int2 vi = ((const int2*)vidx)[e];
    int row = vi.x + ofs;
    int col = vi.y + ofs;
    int p = atomicAdd(&ecnt[col], 1);
    if (p < CAP) ebuf[col * CAP + p] = make_int2(e + 1, row);

    int2 qi = ((const int2*)qidx)[e];
    int g  = qi.y + ofs;
    int pq = atomicAdd(&qcnt[g], 1);
    if (pq < CAP) qbuf[g * CAP + pq] = (e + 1) | ((qi.x == qi.y) ? 0x80000000 : 0);
}

#define KACC(C)                                                          \
    {                                                                    \
        const float4* kp = (const float4*)&sk[wid][C][h20];              \
        float4 k0 = kp[0], k1 = kp[1], k2 = kp[2], k3 = kp[3];           \
        float kk[16] = {k0.x,k0.y,k0.z,k0.w, k1.x,k1.y,k1.z,k1.w,        \
                        k2.x,k2.y,k2.z,k2.w, k3.x,k3.y,k3.z,k3.w};       \
        _Pragma("unroll")                                                \
        for (int i = 0; i < 16; ++i) {                                   \
            ks[i]  += kk[i];                                             \
            kva[i] += kk[i] * vvv[C].x;                                  \
            kvb[i] += kk[i] * vvv[C].y;                                  \
        }                                                                \
    }

#define QOUT(C, TREG)                                                    \
    {                                                                    \
        const float4* qp = (const float4*)&sq[wid][C][h20];              \
        float4 q0 = qp[0], q1 = qp[1], q2 = qp[2], q3 = qp[3];           \
        float qq[16] = {q0.x,q0.y,q0.z,q0.w, q1.x,q1.y,q1.z,q1.w,        \
                        q2.x,q2.y,q2.z,q2.w, q3.x,q3.y,q3.z,q3.w};       \
        float sa = 0.0f, sb = 0.0f, w = 0.0f;                            \
        _Pragma("unroll")                                                \
        for (int i = 0; i < 16; ++i) {                                   \
            sa += qq[i] * kva[i];                                        \
            sb += qq[i] * kvb[i];                                        \
            w  += qq[i] * ks[i];                                         \
        }                                                                \
        float den = (w == 0.0f) ? 1e-5f : w;                             \
        float inv = 1.0f / den;                                          \
        float2 o;                                                        \
        o.x = ((TREG) < 0) ? 0.0f : sa * inv;                            \
        o.y = ((TREG) < 0) ? 0.0f : sb * inv;                            \
        *(float2*)(out + (size_t)(((TREG) & 0x7FFFFFFF) - 1) * DVTOT + f2) = o; \
    }

// One node per WAVE (4 nodes / 256-thread block), no block barriers.
// lane l: head h = l>>3, columns j = 2*(l&7), +1.
__global__ __launch_bounds__(256) void attn_node(
    const float* __restrict__ qv,
    const float* __restrict__ keys,
    const float* __restrict__ vals,
    const int2*  __restrict__ ebuf,
    const int*   __restrict__ qbuf,
    float*       __restrict__ out)
{
    __shared__ float sk[4][4][160];   // [wave][chunk][padded row]
    __shared__ float sq[4][4][160];

    int wid  = threadIdx.x >> 6;
    int lane = threadIdx.x & 63;
    int g    = __builtin_amdgcn_readfirstlane(blockIdx.x * 4 + wid);

    int h20 = (lane >> 3) * 20;
    int f2  = 2 * lane;
    int pf2 = padidx(f2);

    const int2* eb = ebuf + (size_t)g * CAP;
    const int*  qb = qbuf + (size_t)g * CAP;

    // issue both bucket reads up front (scalar, independent)
    int qt[4];
#pragma unroll
    for (int c = 0; c < 4; ++c) qt[c] = qb[c];
    int2 er[4];
#pragma unroll
    for (int c = 0; c < 4; ++c) er[c] = eb[c];

    int nq0 = qt[0] ? (qt[1] ? (qt[2] ? (qt[3] ? 4 : 3) : 2) : 1) : 0;
    if (nq0 == 0) return;                            // wave-uniform
    int dg0 = er[0].x ? (er[1].x ? (er[2].x ? (er[3].x ? 4 : 3) : 2) : 1) : 0;

    // chunk-0 global loads for BOTH phases, issued together
    float2 kkv[4], vvv[4], qqv[4];
#pragma unroll
    for (int c = 0; c < 4; ++c)
        if (c < dg0) {
            kkv[c] = *(const float2*)(keys + (size_t)er[c].y * DVTOT + f2);
            vvv[c] = *(const float2*)(vals + (size_t)(er[c].x - 1) * DVTOT + f2);
        }
#pragma unroll
    for (int c = 0; c < 4; ++c)
        if (c < nq0)
            qqv[c] = *(const float2*)(qv + (size_t)((qt[c] & 0x7FFFFFFF) - 1) * DVTOT + f2);
#pragma unroll
    for (int c = 0; c < 4; ++c)
        if (c < dg0) *(float2*)&sk[wid][c][pf2] = kkv[c];
#pragma unroll
    for (int c = 0; c < 4; ++c)
        if (c < nq0) *(float2*)&sq[wid][c][pf2] = qqv[c];
    __builtin_amdgcn_wave_barrier();

    float kva[16], kvb[16], ks[16];
#pragma unroll
    for (int i = 0; i < 16; ++i) { kva[i] = 0.0f; kvb[i] = 0.0f; ks[i] = 0.0f; }

    // chunk-0 k accumulate
#pragma unroll
    for (int c = 0; c < 4; ++c)
        if (c < dg0) KACC(c);

    // k remainder (deg > 4)
    if (dg0 == 4) {
        for (int base = 4; base < CAP; base += 4) {
            int2 r[4];
#pragma unroll
            for (int c = 0; c < 4; ++c) r[c] = eb[base + c];
            int n = r[0].x ? (r[1].x ? (r[2].x ? (r[3].x ? 4 : 3) : 2) : 1) : 0;
            if (n == 0) break;
#pragma unroll
            for (int c = 0; c < 4; ++c)
                if (c < n) {
                    kkv[c] = *(const float2*)(keys + (size_t)r[c].y * DVTOT + f2);
                    vvv[c] = *(const float2*)(vals + (size_t)(r[c].x - 1) * DVTOT + f2);
                }
            __builtin_amdgcn_wave_barrier();         // WAR fence for sk reuse
#pragma unroll
            for (int c = 0; c < 4; ++c)
                if (c < n) *(float2*)&sk[wid][c][pf2] = kkv[c];
            __builtin_amdgcn_wave_barrier();
#pragma unroll
            for (int c = 0; c < 4; ++c)
                if (c < n) KACC(c);
            if (n < 4) break;
        }
    }

    // q outputs, chunk 0 (rows already staged)
#pragma unroll
    for (int c = 0; c < 4; ++c)
        if (c < nq0) QOUT(c, qt[c]);

    // q remainder (nq > 4)
    if (nq0 == 4) {
        for (int base = 4; base < CAP; base += 4) {
            int t[4];
#pragma unroll
            for (int c = 0; c < 4; ++c) t[c] = qb[base + c];
            int n = t[0] ? (t[1] ? (t[2] ? (t[3] ? 4 : 3) : 2) : 1) : 0;
            if (n == 0) break;
#pragma unroll
            for (int c = 0; c < 4; ++c)
                if (c < n)
                    qqv[c] = *(const float2*)(qv + (size_t)((t[c] & 0x7FFFFFFF) - 1) * DVTOT + f2);
            __builtin_amdgcn_wave_barrier();         // WAR fence for sq reuse
#pragma unroll
            for (int c = 0; c < 4; ++c)
                if (c < n) *(float2*)&sq[wid][c][pf2] = qqv[c];
            __builtin_amdgcn_wave_barrier();
#pragma unroll
            for (int c = 0; c < 4; ++c)
                if (c < n) QOUT(c, t[c]);
            if (n < 4) break;
        }
    }
}

extern "C" void kernel_launch(void* const* d_in, const int* in_sizes, int n_in,
                              void* d_out, int out_size, void* d_ws, size_t ws_size,
                              hipStream_t stream) {
    const float* qv   = (const float*)d_in[0];
    const float* keys = (const float*)d_in[1];
    const float* vals = (const float*)d_in[2];
    const int*   qidx = (const int*)d_in[3];
    const int*   vidx = (const int*)d_in[4];
    float* out = (float*)d_out;

    char* ws = (char*)d_ws;
    int*  ecnt = (int*)ws;                                // NTOT
    int*  qcnt = ecnt + NTOT;                             // NTOT
    int2* ebuf = (int2*)(qcnt + NTOT);                    // NTOT*CAP int2
    int*  qbuf = (int*)(ebuf + (size_t)NTOT * CAP);       // NTOT*CAP int

    zero_ws<<<ZERO_INT4 / 256, 256, 0, stream>>>((int4*)ws);
    fill_all<<<(NV + 255) / 256, 256, 0, stream>>>(qidx, vidx, ecnt, qcnt, ebuf, qbuf);
    attn_node<<<NTOT / 4, 256, 0, stream>>>(qv, keys, vals, ebuf, qbuf, out);
}